// Round 7
// baseline (454.594 us; speedup 1.0000x reference)
//
#include <hip/hip_runtime.h>
#include <hip/hip_bf16.h>

#define N_PTS 50000
#define NNB   32
#define KP    15
#define DIN   64
#define DOUT  1024
#define KDIM  960
#define KDIM_P 1024               // K padded so NKT is even and tail-free
#define NB    16
#define SIGMA_INV (1.0f/0.3f)

#define BM 256
#define BN 128
#define BK 64
#define NKT (KDIM_P/BK)            // 16
#define RB ((N_PTS + BM - 1)/BM)   // 196
#define M_PAD (RB*BM)              // 50176
#define NCB (DOUT/BN)              // 8
#define NWG (RB*NCB)               // 1568, %8 == 0
#define BUFSZ 49152                // A 32KB + B 16KB

typedef __attribute__((ext_vector_type(8))) short bf16x8;
typedef __attribute__((ext_vector_type(4))) float f32x4;

#define GLD16(gsrc, ldst) \
  __builtin_amdgcn_global_load_lds((const __attribute__((address_space(1))) char*)(gsrc), \
                                   (__attribute__((address_space(3))) char*)(ldst), 16, 0, 0)

// ---------------- Kernel 0: W [960][1024] f32 -> Wt [1024][1024] bf16 (K-pad 0)
__global__ __launch_bounds__(256) void wt_kernel(
    const float* __restrict__ W, __hip_bfloat16* __restrict__ Wt) {
  __shared__ float t[64][65];
  int k0 = blockIdx.x * 64;   // 16 tiles -> covers padded K
  int o0 = blockIdx.y * 64;
  int tx = threadIdx.x & 63, ty = threadIdx.x >> 6;
  for (int r = ty; r < 64; r += 4)
    t[r][tx] = (k0 + r < KDIM) ? W[(size_t)(k0 + r)*DOUT + o0 + tx] : 0.0f;
  __syncthreads();
  for (int r = ty; r < 64; r += 4)
    Wt[(size_t)(o0 + r)*KDIM_P + k0 + tx] = __float2bfloat16(t[tx][r]);
}

// ---------------- Kernel 1: KPConv g rows, one WAVE per point ---------------
__global__ __launch_bounds__(256) void kpconv_wave_kernel(
    const float* __restrict__ pos, const float* __restrict__ feats,
    const float* __restrict__ kpts, const int* __restrict__ nidx,
    __hip_bfloat16* __restrict__ g) {
  __shared__ float h_lds[4][NNB][16];
  int tid = threadIdx.x;
  int w = tid >> 6, lane = tid & 63;
  int n = blockIdx.x * 4 + w;
  float acc[KP];
  #pragma unroll
  for (int k = 0; k < KP; ++k) acc[k] = 0.0f;

  if (n < N_PTS) {
    int myj = lane & 31;
    int id0 = nidx[n*NNB + myj];
    float px = pos[n*3+0], py = pos[n*3+1], pz = pos[n*3+2];
    float rx = pos[id0*3+0] - px;
    float ry = pos[id0*3+1] - py;
    float rz = pos[id0*3+2] - pz;
    bool anyact = false;
    int khalf = lane >> 5;
    #pragma unroll
    for (int i = 0; i < 8; ++i) {
      int k = 2*i + khalf;
      if (k < KP) {
        float dx = rx - kpts[k*3+0];
        float dy = ry - kpts[k*3+1];
        float dz = rz - kpts[k*3+2];
        float d = sqrtf(dx*dx + dy*dy + dz*dz);
        float h = 1.0f - d * SIGMA_INV;
        h = h > 0.0f ? h : 0.0f;
        h_lds[w][myj][k] = h;
        anyact |= (h > 0.0f);
      }
    }
    unsigned long long bal = __ballot(anyact);
    unsigned int actj = (unsigned int)(bal | (bal >> 32));
    while (actj) {
      int j = __ffs(actj) - 1;
      actj &= actj - 1;
      int id = __shfl(id0, j);
      float f = feats[(size_t)id*DIN + lane];
      #pragma unroll
      for (int k = 0; k < KP; ++k) acc[k] += h_lds[w][j][k] * f;
    }
  }
  if (n < M_PAD) {
    size_t base = (size_t)n*KDIM_P;
    #pragma unroll
    for (int k = 0; k < 16; ++k)
      g[base + k*DIN + lane] = __float2bfloat16(k < KP ? acc[k] : 0.0f);
  }
}

// ---------------- Kernel 2: pipelined MFMA GEMM (3-buf, vmcnt(6)) + pool -----
// A = g [M_PAD][1024] bf16, B = Wt [1024][1024] bf16. 512 thr = 8 waves (4x2),
// wave owns 64x64 out. 3 LDS tile-buffers; stages for tile t+2 issued during
// tile t into the buffer vacated by t-1. Entry of tile t: vmcnt(6) (t+1's 6
// loads stay in flight) + raw s_barrier. Ledger: outstanding at entry(t) =
// {t:6, t+1:6} for t<15; {t:6} at t=15 -> vmcnt(0).
__global__ __launch_bounds__(512, 2) void gemm_mfma_pool8(
    const __hip_bfloat16* __restrict__ g, const __hip_bfloat16* __restrict__ Wt,
    const int* __restrict__ batch, float* __restrict__ partial) {
  __shared__ __align__(16) char lds[3*BUFSZ];   // 147456: per buf A 32KB | B 16KB
  __shared__ float psum[NB][BN];                // 8KB
  __shared__ int bid[BM];                       // 1KB
  int wg = blockIdx.x;
  int newid = (wg & 7)*(NWG/8) + (wg >> 3);     // XCD-chunked bijective swizzle
  int cb = newid & 7, rb = newid >> 3;
  int r0 = rb*BM, c0 = cb*BN;
  int tid = threadIdx.x;
  int lane = tid & 63, w = tid >> 6;
  int wr = w >> 1, wc = w & 1;                  // 4 x 2 waves, 64x64 out each

  f32x4 acc[4][4] = {};

  // one stage part = 512 chunks of 16B. A: parts 0..3 (256r x 64k), B: 0..1.
  #define STG_A(part, kk2, dA) do {                                            \
    int e = (part)*512 + tid;                                                  \
    int row = e >> 3, c = e & 7;                                               \
    int gc = c ^ (row & 7);                                                    \
    GLD16(g + (size_t)(r0+row)*KDIM_P + (kk2) + gc*8, (dA) + e*16);            \
  } while (0)
  #define STG_B(part, kk2, dB) do {                                            \
    int e = (part)*512 + tid;                                                  \
    int row = e >> 3, c = e & 7;                                               \
    int gc = c ^ (row & 7);                                                    \
    GLD16(Wt + (size_t)(c0+row)*KDIM_P + (kk2) + gc*8, (dB) + e*16);           \
  } while (0)

  // prologue: stage tiles 0 and 1 fully; init psum/bid
  {
    char* dA0 = lds;            char* dB0 = lds + 32768;
    char* dA1 = lds + BUFSZ;    char* dB1 = dA1 + 32768;
    STG_A(0, 0, dA0); STG_A(1, 0, dA0); STG_A(2, 0, dA0); STG_A(3, 0, dA0);
    STG_B(0, 0, dB0); STG_B(1, 0, dB0);
    STG_A(0, BK, dA1); STG_A(1, BK, dA1); STG_A(2, BK, dA1); STG_A(3, BK, dA1);
    STG_B(0, BK, dB1); STG_B(1, BK, dB1);
  }
  if (tid < BM) bid[tid] = (r0 + tid < N_PTS) ? batch[r0 + tid] : -1;
  for (int z = tid; z < NB*BN; z += 512) (&psum[0][0])[z] = 0.0f;

  int cur = 0;
  for (int t = 0; t < NKT; ++t) {
    if (t == NKT-1) { asm volatile("s_waitcnt vmcnt(0)" ::: "memory"); }
    else            { asm volatile("s_waitcnt vmcnt(6)" ::: "memory"); }
    __builtin_amdgcn_s_barrier();
    const char* A = lds + cur*BUFSZ;
    const char* B = A + 32768;
    int nxt = cur + 2; if (nxt >= 3) nxt -= 3;
    char* dA = lds + nxt*BUFSZ;
    char* dB = dA + 32768;
    bool do_stage = (t + 2 < NKT);
    size_t kk2 = (size_t)(t + 2)*BK;

    #pragma unroll
    for (int ks = 0; ks < 2; ++ks) {
      bf16x8 af[4], bfr[4];
      #pragma unroll
      for (int m = 0; m < 4; ++m) {
        int row = wr*64 + m*16 + (lane & 15);
        int sc = (ks*4 + (lane >> 4)) ^ (row & 7);
        af[m] = *(const bf16x8*)(A + row*128 + sc*16);
      }
      #pragma unroll
      for (int n = 0; n < 4; ++n) {
        int row = wc*64 + n*16 + (lane & 15);
        int sc = (ks*4 + (lane >> 4)) ^ (row & 7);
        bfr[n] = *(const bf16x8*)(B + row*128 + sc*16);
      }
      if (do_stage) {
        if (ks == 0) { STG_A(0, kk2, dA); STG_A(1, kk2, dA); STG_A(2, kk2, dA); }
        else         { STG_A(3, kk2, dA); STG_B(0, kk2, dB); STG_B(1, kk2, dB); }
      }
      __builtin_amdgcn_s_barrier();
      __builtin_amdgcn_s_setprio(1);
      #pragma unroll
      for (int m = 0; m < 4; ++m)
        #pragma unroll
        for (int n = 0; n < 4; ++n)
          acc[m][n] = __builtin_amdgcn_mfma_f32_16x16x32_bf16(af[m], bfr[n], acc[m][n], 0, 0, 0);
      __builtin_amdgcn_s_setprio(0);
      __builtin_amdgcn_s_barrier();
    }
    cur += 1; if (cur == 3) cur = 0;
  }

  // ---- epilogue: leaky + deterministic per-batch column sums ----
  int q = lane >> 4;
  #pragma unroll 1
  for (int phase = 0; phase < 16; ++phase) {
    if (wr*4 + q == phase) {
      #pragma unroll
      for (int n = 0; n < 4; ++n) {
        int c = wc*64 + n*16 + (lane & 15);
        float run = 0.0f; int curb = -2;
        #pragma unroll
        for (int m = 0; m < 4; ++m) {
          #pragma unroll
          for (int j = 0; j < 4; ++j) {
            int r = wr*64 + m*16 + q*4 + j;
            int b = bid[r];
            float v = acc[m][n][j];
            v = v > 0.0f ? v : 0.1f*v;
            if (b != curb) { if (curb >= 0) psum[curb][c] += run; run = 0.0f; curb = b; }
            run += v;
          }
        }
        if (curb >= 0) psum[curb][c] += run;
      }
    }
    __syncthreads();
  }
  for (int z = tid; z < NB*BN; z += 512) {
    int b = z >> 7, c = z & 127;
    partial[((size_t)rb*NB + b)*DOUT + c0 + c] = psum[b][c];
  }
}

// ---------------- Kernel 3: reduce partials -> pooled mean -------------------
__global__ __launch_bounds__(256) void reduce_pool_kernel(
    const float* __restrict__ partial, const int* __restrict__ batch,
    float* __restrict__ pooled) {
  int b = blockIdx.y;
  int c = blockIdx.x*256 + threadIdx.x;
  float s0=0.f, s1=0.f, s2=0.f, s3=0.f;
  int rb = 0;
  for (; rb + 4 <= RB; rb += 4) {
    s0 += partial[((size_t)(rb+0)*NB + b)*DOUT + c];
    s1 += partial[((size_t)(rb+1)*NB + b)*DOUT + c];
    s2 += partial[((size_t)(rb+2)*NB + b)*DOUT + c];
    s3 += partial[((size_t)(rb+3)*NB + b)*DOUT + c];
  }
  for (; rb < RB; ++rb) s0 += partial[((size_t)rb*NB + b)*DOUT + c];
  float s = (s0+s1)+(s2+s3);
  int lb, ub;
  { int l = 0, r = N_PTS; while (l < r) { int m = (l+r)>>1; if (batch[m] <  b) l = m+1; else r = m; } lb = l; }
  { int l = 0, r = N_PTS; while (l < r) { int m = (l+r)>>1; if (batch[m] <= b) l = m+1; else r = m; } ub = l; }
  float cnt = (float)(ub - lb);
  pooled[b*DOUT + c] = s / fmaxf(cnt, 1.0f);
}

// ---------------- Kernel 4: fused 3-layer MLP head --------------------------
__global__ __launch_bounds__(512) void mlp_fused_kernel(
    const float* __restrict__ pooled,
    const float* __restrict__ w1, const float* __restrict__ b1,
    const float* __restrict__ w2, const float* __restrict__ b2,
    const float* __restrict__ w3, const float* __restrict__ b3,
    float* __restrict__ out) {
  __shared__ float pl[DOUT];
  __shared__ float hh[512];
  int b = blockIdx.x, o = threadIdx.x;
  for (int i = o; i < DOUT; i += 512) pl[i] = pooled[b*DOUT + i];
  __syncthreads();
  float a = b1[o];
  #pragma unroll 8
  for (int i = 0; i < DOUT; ++i) a += pl[i] * w1[(size_t)i*512 + o];
  hh[o] = fmaxf(a, 0.0f);
  __syncthreads();
  float a2 = 0.0f;
  if (o < 256) {
    a2 = b2[o];
    #pragma unroll 8
    for (int i = 0; i < 512; ++i) a2 += hh[i] * w2[(size_t)i*256 + o];
  }
  __syncthreads();
  if (o < 256) pl[o] = fmaxf(a2, 0.0f);
  __syncthreads();
  if (o < 152) {
    float a3 = b3[o];
    #pragma unroll 8
    for (int i = 0; i < 256; ++i) a3 += pl[i] * w3[i*152 + o];
    out[b*152 + o] = a3;
  }
}

// ---------------- launch -----------------------------------------------------
extern "C" void kernel_launch(void* const* d_in, const int* in_sizes, int n_in,
                              void* d_out, int out_size, void* d_ws, size_t ws_size,
                              hipStream_t stream) {
  (void)in_sizes; (void)n_in; (void)out_size; (void)ws_size;
  const float* pos   = (const float*)d_in[0];
  const float* feats = (const float*)d_in[1];
  const float* kpts  = (const float*)d_in[2];
  const float* kpw   = (const float*)d_in[3];
  const float* w1    = (const float*)d_in[4];
  const float* b1    = (const float*)d_in[5];
  const float* w2    = (const float*)d_in[6];
  const float* b2    = (const float*)d_in[7];
  const float* w3    = (const float*)d_in[8];
  const float* b3    = (const float*)d_in[9];
  const int* nidx    = (const int*)d_in[10];
  const int* batch   = (const int*)d_in[11];
  float* out = (float*)d_out;

  char* ws = (char*)d_ws;
  const size_t off_g       = 0;                          // 50176*1024*2  = 102,760,448
  const size_t off_wt      = 102760448;                  // 1024*1024*2   = 2,097,152
  const size_t off_partial = off_wt + 2097152;           // 196*16*1024*4 = 12,845,056
  const size_t off_pooled  = off_partial + 12845056;     // 65,536
  __hip_bfloat16* g  = (__hip_bfloat16*)(ws + off_g);
  __hip_bfloat16* wt = (__hip_bfloat16*)(ws + off_wt);
  float* partial = (float*)(ws + off_partial);
  float* pooled  = (float*)(ws + off_pooled);

  wt_kernel<<<dim3(KDIM_P/64, DOUT/64), 256, 0, stream>>>(kpw, wt);
  kpconv_wave_kernel<<<M_PAD/4, 256, 0, stream>>>(pos, feats, kpts, nidx, g);
  gemm_mfma_pool8<<<NWG, 512, 0, stream>>>(g, wt, batch, partial);
  reduce_pool_kernel<<<dim3(DOUT/256, NB), 256, 0, stream>>>(partial, batch, pooled);
  mlp_fused_kernel<<<NB, 512, 0, stream>>>(pooled, w1, b1, w2, b2, w3, b3, out);
}

// Round 8
// 261.887 us; speedup vs baseline: 1.7358x; 1.7358x over previous
//
#include <hip/hip_runtime.h>
#include <hip/hip_bf16.h>

#define N_PTS 50000
#define NNB   32
#define KP    15
#define DIN   64
#define DOUT  1024
#define KDIM  (KP*DIN)    // 960
#define NB    16
#define SIGMA_INV (1.0f/0.3f)

#define BM 128
#define BN 128
#define BK 32
#define RB_FULL 392                 // worst-case row blocks (50176 rows)
#define NSEG 196                    // 196*256 = 50176 point segments

typedef __attribute__((ext_vector_type(8))) short bf16x8;
typedef __attribute__((ext_vector_type(4))) float f32x4;

#define GLD16(gsrc, ldst) \
  __builtin_amdgcn_global_load_lds((const __attribute__((address_space(1))) char*)(gsrc), \
                                   (__attribute__((address_space(3))) char*)(ldst), 16, 0, 0)

// ---------------- Kernel 0: W [960][1024] f32 -> Wt [1024][960] bf16 ---------
__global__ __launch_bounds__(256) void wt_kernel(
    const float* __restrict__ W, __hip_bfloat16* __restrict__ Wt) {
  __shared__ float t[64][65];
  int k0 = blockIdx.x * 64;
  int o0 = blockIdx.y * 64;
  int tx = threadIdx.x & 63, ty = threadIdx.x >> 6;
  for (int r = ty; r < 64; r += 4) t[r][tx] = W[(size_t)(k0 + r)*DOUT + o0 + tx];
  __syncthreads();
  for (int r = ty; r < 64; r += 4)
    Wt[(size_t)(o0 + r)*KDIM + k0 + tx] = __float2bfloat16(t[tx][r]);
}

// ---------------- Kernel F: activity flag per point (thread/point) ----------
// Superset test d^2 < sigma^2(+eps): flagged-but-zero rows only add zeros.
__global__ __launch_bounds__(256) void flag_kernel(
    const float* __restrict__ pos, const float* __restrict__ kpts,
    const int* __restrict__ nidx, int* __restrict__ flag,
    int* __restrict__ blockcnt) {
  __shared__ float kp[KP*3];
  __shared__ int cnt;
  int tid = threadIdx.x;
  if (tid < KP*3) kp[tid] = kpts[tid];
  if (tid == 0) cnt = 0;
  __syncthreads();
  int n = blockIdx.x*256 + tid;
  int f = 0;
  if (n < N_PTS) {
    float px = pos[n*3+0], py = pos[n*3+1], pz = pos[n*3+2];
    for (int j = 0; j < NNB && !f; ++j) {
      int id = nidx[n*NNB + j];
      float rx = pos[id*3+0]-px, ry = pos[id*3+1]-py, rz = pos[id*3+2]-pz;
      #pragma unroll
      for (int k = 0; k < KP; ++k) {
        float dx = rx-kp[k*3+0], dy = ry-kp[k*3+1], dz = rz-kp[k*3+2];
        float d2 = dx*dx + dy*dy + dz*dz;
        f |= (d2 < 0.09000002f);
      }
    }
  }
  flag[blockIdx.x*256 + tid] = f;
  unsigned long long bal = __ballot(f != 0);
  if ((tid & 63) == 0) atomicAdd(&cnt, __popcll(bal));
  __syncthreads();
  if (tid == 0) blockcnt[blockIdx.x] = cnt;
}

// ---------------- Kernel S: scan 196 segment counts (1 block) ---------------
__global__ __launch_bounds__(256) void scan_kernel(
    const int* __restrict__ blockcnt, int* __restrict__ blockoff,
    int* __restrict__ mact) {
  __shared__ int s[256];
  int tid = threadIdx.x;
  int own = (tid < NSEG) ? blockcnt[tid] : 0;
  s[tid] = own;
  __syncthreads();
  for (int d = 1; d < 256; d <<= 1) {
    int v = (tid >= d) ? s[tid-d] : 0;
    __syncthreads();
    s[tid] += v;
    __syncthreads();
  }
  if (tid < NSEG) blockoff[tid] = s[tid] - own;   // exclusive
  if (tid == NSEG-1) *mact = s[tid];
}

// ---------------- Kernel C0: stable slot per point + compact batch ids ------
__global__ __launch_bounds__(256) void slot_kernel(
    const int* __restrict__ flag, const int* __restrict__ blockoff,
    const int* __restrict__ batch, int* __restrict__ slot,
    int* __restrict__ bidc) {
  __shared__ int s[256];
  int tid = threadIdx.x;
  int n = blockIdx.x*256 + tid;
  int f = flag[n];
  s[tid] = f;
  __syncthreads();
  for (int d = 1; d < 256; d <<= 1) {
    int v = (tid >= d) ? s[tid-d] : 0;
    __syncthreads();
    s[tid] += v;
    __syncthreads();
  }
  int sl = -1;
  if (f) {
    sl = blockoff[blockIdx.x] + s[tid] - 1;
    if (n < N_PTS) bidc[sl] = batch[n];
  }
  slot[n] = sl;
}

// ---------------- Kernel 1: KPConv, wave/point, compacted writes ------------
__global__ __launch_bounds__(256) void kpconv_compact_kernel(
    const float* __restrict__ pos, const float* __restrict__ feats,
    const float* __restrict__ kpts, const int* __restrict__ nidx,
    const int* __restrict__ slotarr, __hip_bfloat16* __restrict__ g) {
  __shared__ float h_lds[4][NNB][16];
  int tid = threadIdx.x;
  int w = tid >> 6, lane = tid & 63;
  int n = blockIdx.x * 4 + w;
  if (n >= N_PTS) return;
  int sl = slotarr[n];
  if (sl < 0) return;                    // wave-uniform: inactive point

  float acc[KP];
  #pragma unroll
  for (int k = 0; k < KP; ++k) acc[k] = 0.0f;

  int myj = lane & 31;
  int id0 = nidx[n*NNB + myj];
  float px = pos[n*3+0], py = pos[n*3+1], pz = pos[n*3+2];
  float rx = pos[id0*3+0] - px;
  float ry = pos[id0*3+1] - py;
  float rz = pos[id0*3+2] - pz;
  bool anyact = false;
  int khalf = lane >> 5;
  #pragma unroll
  for (int i = 0; i < 8; ++i) {
    int k = 2*i + khalf;
    if (k < KP) {
      float dx = rx - kpts[k*3+0];
      float dy = ry - kpts[k*3+1];
      float dz = rz - kpts[k*3+2];
      float d = sqrtf(dx*dx + dy*dy + dz*dz);
      float h = 1.0f - d * SIGMA_INV;
      h = h > 0.0f ? h : 0.0f;
      h_lds[w][myj][k] = h;
      anyact |= (h > 0.0f);
    }
  }
  unsigned long long bal = __ballot(anyact);
  unsigned int actj = (unsigned int)(bal | (bal >> 32));
  while (actj) {
    int j = __ffs(actj) - 1;
    actj &= actj - 1;
    int id = __shfl(id0, j);
    float f = feats[(size_t)id*DIN + lane];
    #pragma unroll
    for (int k = 0; k < KP; ++k) acc[k] += h_lds[w][j][k] * f;
  }
  size_t base = (size_t)sl*KDIM;
  #pragma unroll
  for (int k = 0; k < KP; ++k)
    g[base + k*DIN + lane] = __float2bfloat16(acc[k]);
}

// ---------------- Kernel 2: MFMA GEMM over compacted rows + fused pool -------
// R2's verified structure: 128x128, BK=32, 4 waves 2x2, slot-XOR swizzle.
// grid = (rb=392, cb=8): linear id = rb + 392*cb, 392%8==0 -> the 8 blocks
// sharing an A-panel land on ONE XCD (panel fetched once per HBM).
// Blocks past M_active write zero partials and exit; tail rows masked bid=-1.
__global__ __launch_bounds__(256) void gemm_mfma_pool(
    const __hip_bfloat16* __restrict__ g, const __hip_bfloat16* __restrict__ Wt,
    const int* __restrict__ bidc, const int* __restrict__ mact,
    float* __restrict__ partial) {
  __shared__ __align__(16) char lA[BM*64];   // 8KB
  __shared__ __align__(16) char lB[BN*64];   // 8KB
  __shared__ float psum[NB][BN];             // 8KB
  __shared__ int bid[BM];
  int rb = blockIdx.x, cb = blockIdx.y;
  int Ma = *mact;
  int r0 = rb*BM, c0 = cb*BN;
  int tid = threadIdx.x;
  if (r0 >= Ma) {
    for (int z = tid; z < NB*BN; z += 256)
      partial[((size_t)rb*NB + (z >> 7))*DOUT + c0 + (z & 127)] = 0.0f;
    return;
  }
  int lane = tid & 63, w = tid >> 6;
  int wr = w >> 1, wc = w & 1;

  f32x4 acc[4][4] = {};

  for (int k0 = 0; k0 < KDIM; k0 += BK) {
    #pragma unroll
    for (int p = 0; p < 2; ++p) {
      int i = p*256 + tid;
      int row = i >> 2, slot = i & 3;
      int kg = slot ^ ((row >> 1) & 3);
      GLD16(g  + (size_t)(r0+row)*KDIM + k0 + kg*8, lA + i*16);
      GLD16(Wt + (size_t)(c0+row)*KDIM + k0 + kg*8, lB + i*16);
    }
    __syncthreads();
    bf16x8 af[4], bfr[4];
    #pragma unroll
    for (int m = 0; m < 4; ++m) {
      int row = wr*64 + m*16 + (lane & 15);
      int slot = (lane >> 4) ^ ((row >> 1) & 3);
      af[m] = *(const bf16x8*)(lA + row*64 + slot*16);
    }
    #pragma unroll
    for (int n = 0; n < 4; ++n) {
      int row = wc*64 + n*16 + (lane & 15);
      int slot = (lane >> 4) ^ ((row >> 1) & 3);
      bfr[n] = *(const bf16x8*)(lB + row*64 + slot*16);
    }
    #pragma unroll
    for (int m = 0; m < 4; ++m)
      #pragma unroll
      for (int n = 0; n < 4; ++n)
        acc[m][n] = __builtin_amdgcn_mfma_f32_16x16x32_bf16(af[m], bfr[n], acc[m][n], 0, 0, 0);
    __syncthreads();
  }

  // ---- epilogue: leaky + deterministic per-batch column sums ----
  if (tid < BM) bid[tid] = (r0 + tid < Ma) ? bidc[r0 + tid] : -1;
  for (int z = tid; z < NB*BN; z += 256) (&psum[0][0])[z] = 0.0f;
  __syncthreads();
  int q = lane >> 4;
  #pragma unroll 1
  for (int phase = 0; phase < 8; ++phase) {
    if (wr*4 + q == phase) {
      #pragma unroll
      for (int n = 0; n < 4; ++n) {
        int c = wc*64 + n*16 + (lane & 15);
        float run = 0.0f; int curb = -2;
        #pragma unroll
        for (int m = 0; m < 4; ++m) {
          #pragma unroll
          for (int j = 0; j < 4; ++j) {
            int r = wr*64 + m*16 + q*4 + j;
            int b = bid[r];
            float v = acc[m][n][j];
            v = v > 0.0f ? v : 0.1f*v;
            if (b != curb) { if (curb >= 0) psum[curb][c] += run; run = 0.0f; curb = b; }
            run += v;
          }
        }
        if (curb >= 0) psum[curb][c] += run;
      }
    }
    __syncthreads();
  }
  for (int z = tid; z < NB*BN; z += 256) {
    int b = z >> 7, c = z & 127;
    partial[((size_t)rb*NB + b)*DOUT + c0 + c] = psum[b][c];
  }
}

// ---------------- Kernel 3: reduce partials -> pooled mean -------------------
__global__ __launch_bounds__(256) void reduce_pool_kernel(
    const float* __restrict__ partial, const int* __restrict__ batch,
    float* __restrict__ pooled) {
  int b = blockIdx.y;
  int c = blockIdx.x*256 + threadIdx.x;
  float s0=0.f, s1=0.f, s2=0.f, s3=0.f;
  int rb = 0;
  for (; rb + 4 <= RB_FULL; rb += 4) {
    s0 += partial[((size_t)(rb+0)*NB + b)*DOUT + c];
    s1 += partial[((size_t)(rb+1)*NB + b)*DOUT + c];
    s2 += partial[((size_t)(rb+2)*NB + b)*DOUT + c];
    s3 += partial[((size_t)(rb+3)*NB + b)*DOUT + c];
  }
  for (; rb < RB_FULL; ++rb) s0 += partial[((size_t)rb*NB + b)*DOUT + c];
  float s = (s0+s1)+(s2+s3);
  int lb, ub;
  { int l = 0, r = N_PTS; while (l < r) { int m = (l+r)>>1; if (batch[m] <  b) l = m+1; else r = m; } lb = l; }
  { int l = 0, r = N_PTS; while (l < r) { int m = (l+r)>>1; if (batch[m] <= b) l = m+1; else r = m; } ub = l; }
  float cnt = (float)(ub - lb);
  pooled[b*DOUT + c] = s / fmaxf(cnt, 1.0f);
}

// ---------------- Kernel 4: fused 3-layer MLP head --------------------------
__global__ __launch_bounds__(512) void mlp_fused_kernel(
    const float* __restrict__ pooled,
    const float* __restrict__ w1, const float* __restrict__ b1,
    const float* __restrict__ w2, const float* __restrict__ b2,
    const float* __restrict__ w3, const float* __restrict__ b3,
    float* __restrict__ out) {
  __shared__ float pl[DOUT];
  __shared__ float hh[512];
  int b = blockIdx.x, o = threadIdx.x;
  for (int i = o; i < DOUT; i += 512) pl[i] = pooled[b*DOUT + i];
  __syncthreads();
  float a = b1[o];
  #pragma unroll 8
  for (int i = 0; i < DOUT; ++i) a += pl[i] * w1[(size_t)i*512 + o];
  hh[o] = fmaxf(a, 0.0f);
  __syncthreads();
  float a2 = 0.0f;
  if (o < 256) {
    a2 = b2[o];
    #pragma unroll 8
    for (int i = 0; i < 512; ++i) a2 += hh[i] * w2[(size_t)i*256 + o];
  }
  __syncthreads();
  if (o < 256) pl[o] = fmaxf(a2, 0.0f);
  __syncthreads();
  if (o < 152) {
    float a3 = b3[o];
    #pragma unroll 8
    for (int i = 0; i < 256; ++i) a3 += pl[i] * w3[i*152 + o];
    out[b*152 + o] = a3;
  }
}

// ---------------- launch -----------------------------------------------------
extern "C" void kernel_launch(void* const* d_in, const int* in_sizes, int n_in,
                              void* d_out, int out_size, void* d_ws, size_t ws_size,
                              hipStream_t stream) {
  (void)in_sizes; (void)n_in; (void)out_size; (void)ws_size;
  const float* pos   = (const float*)d_in[0];
  const float* feats = (const float*)d_in[1];
  const float* kpts  = (const float*)d_in[2];
  const float* kpw   = (const float*)d_in[3];
  const float* w1    = (const float*)d_in[4];
  const float* b1    = (const float*)d_in[5];
  const float* w2    = (const float*)d_in[6];
  const float* b2    = (const float*)d_in[7];
  const float* w3    = (const float*)d_in[8];
  const float* b3    = (const float*)d_in[9];
  const int* nidx    = (const int*)d_in[10];
  const int* batch   = (const int*)d_in[11];
  float* out = (float*)d_out;

  char* ws = (char*)d_ws;
  const size_t off_g        = 0;                         // 50176*960*2   = 96,337,920
  const size_t off_bidc     = 96337920;                  // 50176*4       = 200,704
  const size_t off_slot     = off_bidc + 200704;         // 200,704
  const size_t off_flag     = off_slot + 200704;         // 200,704
  const size_t off_bcnt     = off_flag + 200704;         // 1024 (196 used)
  const size_t off_boff     = off_bcnt + 1024;           // 1024
  const size_t off_mact     = off_boff + 1024;           // 64
  const size_t off_wt       = off_mact + 64;             // 1024*960*2    = 1,966,080
  const size_t off_partial  = off_wt + 1966080;          // 392*16*1024*4 = 25,690,112
  const size_t off_pooled   = off_partial + 25690112;    // 65,536
  __hip_bfloat16* g  = (__hip_bfloat16*)(ws + off_g);
  int* bidc    = (int*)(ws + off_bidc);
  int* slot    = (int*)(ws + off_slot);
  int* flag    = (int*)(ws + off_flag);
  int* bcnt    = (int*)(ws + off_bcnt);
  int* boff    = (int*)(ws + off_boff);
  int* mact    = (int*)(ws + off_mact);
  __hip_bfloat16* wt = (__hip_bfloat16*)(ws + off_wt);
  float* partial = (float*)(ws + off_partial);
  float* pooled  = (float*)(ws + off_pooled);

  wt_kernel<<<dim3(KDIM/64, DOUT/64), 256, 0, stream>>>(kpw, wt);
  flag_kernel<<<NSEG, 256, 0, stream>>>(pos, kpts, nidx, flag, bcnt);
  scan_kernel<<<1, 256, 0, stream>>>(bcnt, boff, mact);
  slot_kernel<<<NSEG, 256, 0, stream>>>(flag, boff, batch, slot, bidc);
  kpconv_compact_kernel<<<N_PTS/4, 256, 0, stream>>>(pos, feats, kpts, nidx, slot, g);
  gemm_mfma_pool<<<dim3(RB_FULL, 8), 256, 0, stream>>>(g, wt, bidc, mact, partial);
  reduce_pool_kernel<<<dim3(DOUT/256, NB), 256, 0, stream>>>(partial, batch, pooled);
  mlp_fused_kernel<<<NB, 512, 0, stream>>>(pooled, w1, b1, w2, b2, w3, b3, out);
}

// Round 9
// 214.048 us; speedup vs baseline: 2.1238x; 1.2235x over previous
//
#include <hip/hip_runtime.h>
#include <hip/hip_bf16.h>

#define N_PTS 50000
#define NNB   32
#define KP    15
#define DIN   64
#define DOUT  1024
#define KDIM  (KP*DIN)    // 960
#define NB    16
#define SIGMA_INV (1.0f/0.3f)

#define BM 128
#define BN 128
#define BK 32
#define RB_FULL 392                 // worst-case row blocks (50176 rows)
#define NSEG 196                    // 256-point segments (50176 padded)

typedef __attribute__((ext_vector_type(8))) short bf16x8;
typedef __attribute__((ext_vector_type(4))) float f32x4;

#define GLD16(gsrc, ldst) \
  __builtin_amdgcn_global_load_lds((const __attribute__((address_space(1))) char*)(gsrc), \
                                   (__attribute__((address_space(3))) char*)(ldst), 16, 0, 0)

// ---------------- Kernel 0: W [960][1024] f32 -> Wt [1024][960] bf16 ---------
__global__ __launch_bounds__(256) void wt_kernel(
    const float* __restrict__ W, __hip_bfloat16* __restrict__ Wt) {
  __shared__ float t[64][65];
  int k0 = blockIdx.x * 64;
  int o0 = blockIdx.y * 64;
  int tx = threadIdx.x & 63, ty = threadIdx.x >> 6;
  for (int r = ty; r < 64; r += 4) t[r][tx] = W[(size_t)(k0 + r)*DOUT + o0 + tx];
  __syncthreads();
  for (int r = ty; r < 64; r += 4)
    Wt[(size_t)(o0 + r)*KDIM + k0 + tx] = __float2bfloat16(t[tx][r]);
}

// ---------------- Kernel F: activity flag, one WAVE per point ---------------
// Superset test d^2 < sigma^2(+eps): flagged-but-zero rows only add zeros.
__global__ __launch_bounds__(256) void flagw_kernel(
    const float* __restrict__ pos, const float* __restrict__ kpts,
    const int* __restrict__ nidx, int* __restrict__ flag,
    int* __restrict__ bcnt) {
  __shared__ int cnts;
  int tid = threadIdx.x;
  int w = tid >> 6, lane = tid & 63;
  if (tid == 0) cnts = 0;
  __syncthreads();
  int n = blockIdx.x*4 + w;
  if (n < N_PTS) {
    int myj = lane & 31;
    int id0 = nidx[n*NNB + myj];
    float px = pos[n*3+0], py = pos[n*3+1], pz = pos[n*3+2];
    float rx = pos[id0*3+0] - px;
    float ry = pos[id0*3+1] - py;
    float rz = pos[id0*3+2] - pz;
    bool anyact = false;
    int khalf = lane >> 5;
    #pragma unroll
    for (int i = 0; i < 8; ++i) {
      int k = 2*i + khalf;
      if (k < KP) {
        float dx = rx - kpts[k*3+0];
        float dy = ry - kpts[k*3+1];
        float dz = rz - kpts[k*3+2];
        float d2 = dx*dx + dy*dy + dz*dz;
        anyact |= (d2 < 0.09000002f);
      }
    }
    unsigned long long bal = __ballot(anyact);
    int f = (bal != 0ull) ? 1 : 0;
    if (lane == 0) {
      flag[n] = f;
      if (f) atomicAdd(&cnts, 1);
    }
  }
  __syncthreads();
  if (tid == 0) atomicAdd(&bcnt[blockIdx.x >> 6], cnts);
}

// ---------------- Kernel S: scan 196 segment counts (1 block) ---------------
__global__ __launch_bounds__(256) void scan_kernel(
    const int* __restrict__ blockcnt, int* __restrict__ blockoff,
    int* __restrict__ mact) {
  __shared__ int s[256];
  int tid = threadIdx.x;
  int own = (tid < NSEG) ? blockcnt[tid] : 0;
  s[tid] = own;
  __syncthreads();
  for (int d = 1; d < 256; d <<= 1) {
    int v = (tid >= d) ? s[tid-d] : 0;
    __syncthreads();
    s[tid] += v;
    __syncthreads();
  }
  if (tid < NSEG) blockoff[tid] = s[tid] - own;   // exclusive
  if (tid == NSEG-1) *mact = s[tid];
}

// ---------------- Kernel C0: stable slot per point + compact batch ids ------
__global__ __launch_bounds__(256) void slot_kernel(
    const int* __restrict__ flag, const int* __restrict__ blockoff,
    const int* __restrict__ batch, int* __restrict__ slot,
    int* __restrict__ bidc) {
  __shared__ int s[256];
  int tid = threadIdx.x;
  int n = blockIdx.x*256 + tid;
  int f = (n < N_PTS) ? flag[n] : 0;
  s[tid] = f;
  __syncthreads();
  for (int d = 1; d < 256; d <<= 1) {
    int v = (tid >= d) ? s[tid-d] : 0;
    __syncthreads();
    s[tid] += v;
    __syncthreads();
  }
  int sl = -1;
  if (f) {
    sl = blockoff[blockIdx.x] + s[tid] - 1;
    bidc[sl] = batch[n];
  }
  if (n < N_PTS + 176) slot[n] = sl;
}

// ---------------- Kernel 1: KPConv, wave/point, compacted writes ------------
__global__ __launch_bounds__(256) void kpconv_compact_kernel(
    const float* __restrict__ pos, const float* __restrict__ feats,
    const float* __restrict__ kpts, const int* __restrict__ nidx,
    const int* __restrict__ slotarr, __hip_bfloat16* __restrict__ g) {
  __shared__ float h_lds[4][NNB][16];
  int tid = threadIdx.x;
  int w = tid >> 6, lane = tid & 63;
  int n = blockIdx.x * 4 + w;
  if (n >= N_PTS) return;
  int sl = slotarr[n];
  if (sl < 0) return;                    // wave-uniform: inactive point

  float acc[KP];
  #pragma unroll
  for (int k = 0; k < KP; ++k) acc[k] = 0.0f;

  int myj = lane & 31;
  int id0 = nidx[n*NNB + myj];
  float px = pos[n*3+0], py = pos[n*3+1], pz = pos[n*3+2];
  float rx = pos[id0*3+0] - px;
  float ry = pos[id0*3+1] - py;
  float rz = pos[id0*3+2] - pz;
  bool anyact = false;
  int khalf = lane >> 5;
  #pragma unroll
  for (int i = 0; i < 8; ++i) {
    int k = 2*i + khalf;
    if (k < KP) {
      float dx = rx - kpts[k*3+0];
      float dy = ry - kpts[k*3+1];
      float dz = rz - kpts[k*3+2];
      float d = sqrtf(dx*dx + dy*dy + dz*dz);
      float h = 1.0f - d * SIGMA_INV;
      h = h > 0.0f ? h : 0.0f;
      h_lds[w][myj][k] = h;
      anyact |= (h > 0.0f);
    }
  }
  unsigned long long bal = __ballot(anyact);
  unsigned int actj = (unsigned int)(bal | (bal >> 32));
  while (actj) {
    int j = __ffs(actj) - 1;
    actj &= actj - 1;
    int id = __shfl(id0, j);
    float f = feats[(size_t)id*DIN + lane];
    #pragma unroll
    for (int k = 0; k < KP; ++k) acc[k] += h_lds[w][j][k] * f;
  }
  size_t base = (size_t)sl*KDIM;
  #pragma unroll
  for (int k = 0; k < KP; ++k)
    g[base + k*DIN + lane] = __float2bfloat16(acc[k]);
}

// ---------------- Kernel 2: MFMA GEMM over compacted rows + fused pool -------
// R2's verified structure: 128x128, BK=32, 4 waves 2x2, slot-XOR swizzle.
// grid (rb=392, cb=8): linear id = rb + 392*cb, 392%8==0 -> the 8 blocks
// sharing an A-panel land on ONE XCD. Inactive rb blocks return (no writes).
__global__ __launch_bounds__(256) void gemm_mfma_pool(
    const __hip_bfloat16* __restrict__ g, const __hip_bfloat16* __restrict__ Wt,
    const int* __restrict__ bidc, const int* __restrict__ mact,
    float* __restrict__ partial) {
  __shared__ __align__(16) char lA[BM*64];   // 8KB
  __shared__ __align__(16) char lB[BN*64];   // 8KB
  __shared__ float psum[NB][BN];             // 8KB
  __shared__ int bid[BM];
  int rb = blockIdx.x, cb = blockIdx.y;
  int Ma = *mact;
  int r0 = rb*BM, c0 = cb*BN;
  int tid = threadIdx.x;
  if (r0 >= Ma) return;                      // reduce kernel skips these too
  int lane = tid & 63, w = tid >> 6;
  int wr = w >> 1, wc = w & 1;

  f32x4 acc[4][4] = {};

  for (int k0 = 0; k0 < KDIM; k0 += BK) {
    #pragma unroll
    for (int p = 0; p < 2; ++p) {
      int i = p*256 + tid;
      int row = i >> 2, slot = i & 3;
      int kg = slot ^ ((row >> 1) & 3);
      GLD16(g  + (size_t)(r0+row)*KDIM + k0 + kg*8, lA + i*16);
      GLD16(Wt + (size_t)(c0+row)*KDIM + k0 + kg*8, lB + i*16);
    }
    __syncthreads();
    bf16x8 af[4], bfr[4];
    #pragma unroll
    for (int m = 0; m < 4; ++m) {
      int row = wr*64 + m*16 + (lane & 15);
      int slot = (lane >> 4) ^ ((row >> 1) & 3);
      af[m] = *(const bf16x8*)(lA + row*64 + slot*16);
    }
    #pragma unroll
    for (int n = 0; n < 4; ++n) {
      int row = wc*64 + n*16 + (lane & 15);
      int slot = (lane >> 4) ^ ((row >> 1) & 3);
      bfr[n] = *(const bf16x8*)(lB + row*64 + slot*16);
    }
    #pragma unroll
    for (int m = 0; m < 4; ++m)
      #pragma unroll
      for (int n = 0; n < 4; ++n)
        acc[m][n] = __builtin_amdgcn_mfma_f32_16x16x32_bf16(af[m], bfr[n], acc[m][n], 0, 0, 0);
    __syncthreads();
  }

  // ---- epilogue: leaky + deterministic per-batch column sums ----
  if (tid < BM) bid[tid] = (r0 + tid < Ma) ? bidc[r0 + tid] : -1;
  for (int z = tid; z < NB*BN; z += 256) (&psum[0][0])[z] = 0.0f;
  __syncthreads();
  int q = lane >> 4;
  #pragma unroll 1
  for (int phase = 0; phase < 8; ++phase) {
    if (wr*4 + q == phase) {
      #pragma unroll
      for (int n = 0; n < 4; ++n) {
        int c = wc*64 + n*16 + (lane & 15);
        float run = 0.0f; int curb = -2;
        #pragma unroll
        for (int m = 0; m < 4; ++m) {
          #pragma unroll
          for (int j = 0; j < 4; ++j) {
            int r = wr*64 + m*16 + q*4 + j;
            int b = bid[r];
            float v = acc[m][n][j];
            v = v > 0.0f ? v : 0.1f*v;
            if (b != curb) { if (curb >= 0) psum[curb][c] += run; run = 0.0f; curb = b; }
            run += v;
          }
        }
        if (curb >= 0) psum[curb][c] += run;
      }
    }
    __syncthreads();
  }
  for (int z = tid; z < NB*BN; z += 256) {
    int b = z >> 7, c = z & 127;
    partial[((size_t)rb*NB + b)*DOUT + c0 + c] = psum[b][c];
  }
}

// ---------------- Kernel 3: reduce ACTIVE partials -> pooled mean ------------
__global__ __launch_bounds__(256) void reduce_pool_kernel(
    const float* __restrict__ partial, const int* __restrict__ batch,
    const int* __restrict__ mact, float* __restrict__ pooled) {
  int b = blockIdx.y;
  int c = blockIdx.x*256 + threadIdx.x;
  int nact = (*mact + BM - 1) / BM;
  float s0=0.f, s1=0.f, s2=0.f, s3=0.f;
  int rb = 0;
  for (; rb + 4 <= nact; rb += 4) {
    s0 += partial[((size_t)(rb+0)*NB + b)*DOUT + c];
    s1 += partial[((size_t)(rb+1)*NB + b)*DOUT + c];
    s2 += partial[((size_t)(rb+2)*NB + b)*DOUT + c];
    s3 += partial[((size_t)(rb+3)*NB + b)*DOUT + c];
  }
  for (; rb < nact; ++rb) s0 += partial[((size_t)rb*NB + b)*DOUT + c];
  float s = (s0+s1)+(s2+s3);
  int lb, ub;
  { int l = 0, r = N_PTS; while (l < r) { int m = (l+r)>>1; if (batch[m] <  b) l = m+1; else r = m; } lb = l; }
  { int l = 0, r = N_PTS; while (l < r) { int m = (l+r)>>1; if (batch[m] <= b) l = m+1; else r = m; } ub = l; }
  float cnt = (float)(ub - lb);
  pooled[b*DOUT + c] = s / fmaxf(cnt, 1.0f);
}

// ---------------- MLP: split-K for parallelism ------------------------------
// Layer 1: grid (s=8, b=16), 512 thr. part1[b][s][o] = sum_{i in 128-slice}.
__global__ __launch_bounds__(512) void mlpA_kernel(
    const float* __restrict__ pooled, const float* __restrict__ w1,
    float* __restrict__ part1) {
  __shared__ float pl[128];
  int s = blockIdx.x, b = blockIdx.y;
  int o = threadIdx.x;
  if (o < 128) pl[o] = pooled[b*DOUT + s*128 + o];
  __syncthreads();
  float acc = 0.0f;
  #pragma unroll 8
  for (int i = 0; i < 128; ++i) acc += pl[i] * w1[(size_t)(s*128 + i)*512 + o];
  part1[((size_t)b*8 + s)*512 + o] = acc;
}

// Layer 2: grid (s2=4, b=16), 256 thr. Reduces its own h1-slice, then slice-dot.
__global__ __launch_bounds__(256) void mlpB_kernel(
    const float* __restrict__ part1, const float* __restrict__ b1,
    const float* __restrict__ w2, float* __restrict__ part2) {
  __shared__ float hs[128];
  int s2 = blockIdx.x, b = blockIdx.y;
  int t = threadIdx.x;
  if (t < 128) {
    int i2 = s2*128 + t;
    float v = b1[i2];
    #pragma unroll
    for (int s = 0; s < 8; ++s) v += part1[((size_t)b*8 + s)*512 + i2];
    hs[t] = fmaxf(v, 0.0f);
  }
  __syncthreads();
  float acc = 0.0f;
  #pragma unroll 8
  for (int j = 0; j < 128; ++j) acc += hs[j] * w2[(size_t)(s2*128 + j)*256 + t];
  part2[((size_t)b*4 + s2)*256 + t] = acc;
}

// Layer 3: grid 16, 256 thr. Reduce h2, final 152-wide output.
__global__ __launch_bounds__(256) void mlpC_kernel(
    const float* __restrict__ part2, const float* __restrict__ b2,
    const float* __restrict__ w3, const float* __restrict__ b3,
    float* __restrict__ out) {
  __shared__ float h2l[256];
  int b = blockIdx.x;
  int t = threadIdx.x;
  float v = b2[t];
  #pragma unroll
  for (int s2 = 0; s2 < 4; ++s2) v += part2[((size_t)b*4 + s2)*256 + t];
  h2l[t] = fmaxf(v, 0.0f);
  __syncthreads();
  if (t < 152) {
    float acc = b3[t];
    #pragma unroll 8
    for (int i = 0; i < 256; ++i) acc += h2l[i] * w3[i*152 + t];
    out[b*152 + t] = acc;
  }
}

// ---------------- launch -----------------------------------------------------
extern "C" void kernel_launch(void* const* d_in, const int* in_sizes, int n_in,
                              void* d_out, int out_size, void* d_ws, size_t ws_size,
                              hipStream_t stream) {
  (void)in_sizes; (void)n_in; (void)out_size; (void)ws_size;
  const float* pos   = (const float*)d_in[0];
  const float* feats = (const float*)d_in[1];
  const float* kpts  = (const float*)d_in[2];
  const float* kpw   = (const float*)d_in[3];
  const float* w1    = (const float*)d_in[4];
  const float* b1    = (const float*)d_in[5];
  const float* w2    = (const float*)d_in[6];
  const float* b2    = (const float*)d_in[7];
  const float* w3    = (const float*)d_in[8];
  const float* b3    = (const float*)d_in[9];
  const int* nidx    = (const int*)d_in[10];
  const int* batch   = (const int*)d_in[11];
  float* out = (float*)d_out;

  char* ws = (char*)d_ws;
  const size_t off_g        = 0;                         // 50176*960*2   = 96,337,920
  const size_t off_bidc     = 96337920;                  // 50176*4       = 200,704
  const size_t off_slot     = off_bidc + 200704;         // 200,704
  const size_t off_flag     = off_slot + 200704;         // 200,704
  const size_t off_bcnt     = off_flag + 200704;         // 1024 (196 used)
  const size_t off_boff     = off_bcnt + 1024;           // 1024
  const size_t off_mact     = off_boff + 1024;           // 64
  const size_t off_wt       = off_mact + 64;             // 1024*960*2    = 1,966,080
  const size_t off_partial  = off_wt + 1966080;          // 392*16*1024*4 = 25,690,112
  const size_t off_pooled   = off_partial + 25690112;    // 65,536
  const size_t off_p1       = off_pooled + 65536;        // 16*8*512*4 = 262,144
  const size_t off_p2       = off_p1 + 262144;           // 16*4*256*4 = 65,536
  __hip_bfloat16* g  = (__hip_bfloat16*)(ws + off_g);
  int* bidc    = (int*)(ws + off_bidc);
  int* slot    = (int*)(ws + off_slot);
  int* flag    = (int*)(ws + off_flag);
  int* bcnt    = (int*)(ws + off_bcnt);
  int* boff    = (int*)(ws + off_boff);
  int* mact    = (int*)(ws + off_mact);
  __hip_bfloat16* wt = (__hip_bfloat16*)(ws + off_wt);
  float* partial = (float*)(ws + off_partial);
  float* pooled  = (float*)(ws + off_pooled);
  float* part1   = (float*)(ws + off_p1);
  float* part2   = (float*)(ws + off_p2);

  hipMemsetAsync(bcnt, 0, 1024, stream);
  wt_kernel<<<dim3(KDIM/64, DOUT/64), 256, 0, stream>>>(kpw, wt);
  flagw_kernel<<<N_PTS/4, 256, 0, stream>>>(pos, kpts, nidx, flag, bcnt);
  scan_kernel<<<1, 256, 0, stream>>>(bcnt, boff, mact);
  slot_kernel<<<NSEG, 256, 0, stream>>>(flag, boff, batch, slot, bidc);
  kpconv_compact_kernel<<<N_PTS/4, 256, 0, stream>>>(pos, feats, kpts, nidx, slot, g);
  gemm_mfma_pool<<<dim3(RB_FULL, 8), 256, 0, stream>>>(g, wt, bidc, mact, partial);
  reduce_pool_kernel<<<dim3(DOUT/256, NB), 256, 0, stream>>>(partial, batch, mact, pooled);
  mlpA_kernel<<<dim3(8, NB), 512, 0, stream>>>(pooled, w1, part1);
  mlpB_kernel<<<dim3(4, NB), 256, 0, stream>>>(part1, b1, w2, part2);
  mlpC_kernel<<<NB, 256, 0, stream>>>(part2, b2, w3, b3, out);
}

// Round 10
// 203.822 us; speedup vs baseline: 2.2303x; 1.0502x over previous
//
#include <hip/hip_runtime.h>
#include <hip/hip_bf16.h>

#define N_PTS 50000
#define NNB   32
#define KP    15
#define DIN   64
#define DOUT  1024
#define KDIM  (KP*DIN)    // 960
#define NB    16
#define SIGMA_INV (1.0f/0.3f)

#define BM 128
#define BN 64
#define BK 32
#define RB_FULL 392                 // worst-case row blocks (50176 rows)
#define NSEG 196                    // 256-point segments

typedef __attribute__((ext_vector_type(8))) short bf16x8;
typedef __attribute__((ext_vector_type(4))) float f32x4;

#define GLD16(gsrc, ldst) \
  __builtin_amdgcn_global_load_lds((const __attribute__((address_space(1))) char*)(gsrc), \
                                   (__attribute__((address_space(3))) char*)(ldst), 16, 0, 0)

// ---------------- Kernel 0: W [960][1024] f32 -> Wt [1024][960] bf16 ---------
__global__ __launch_bounds__(256) void wt_kernel(
    const float* __restrict__ W, __hip_bfloat16* __restrict__ Wt) {
  __shared__ float t[64][65];
  int k0 = blockIdx.x * 64;
  int o0 = blockIdx.y * 64;
  int tx = threadIdx.x & 63, ty = threadIdx.x >> 6;
  for (int r = ty; r < 64; r += 4) t[r][tx] = W[(size_t)(k0 + r)*DOUT + o0 + tx];
  __syncthreads();
  for (int r = ty; r < 64; r += 4)
    Wt[(size_t)(o0 + r)*KDIM + k0 + tx] = __float2bfloat16(t[tx][r]);
}

// ---------------- Kernel 1: KPConv full — h for all points, flag + g row ----
// One wave per point. Computes exact h; if any h>0: accumulates and writes
// g[n] (UNCOMPACTED row index n). flag[n] + per-segment counts for the scan.
__global__ __launch_bounds__(256) void kpconv_full_kernel(
    const float* __restrict__ pos, const float* __restrict__ feats,
    const float* __restrict__ kpts, const int* __restrict__ nidx,
    __hip_bfloat16* __restrict__ g, int* __restrict__ flag,
    int* __restrict__ bcnt) {
  __shared__ float h_lds[4][NNB][16];
  __shared__ int cnts;
  int tid = threadIdx.x;
  int w = tid >> 6, lane = tid & 63;
  if (tid == 0) cnts = 0;
  __syncthreads();
  int n = blockIdx.x * 4 + w;
  if (n < N_PTS) {
    int myj = lane & 31;
    int id0 = nidx[n*NNB + myj];
    float px = pos[n*3+0], py = pos[n*3+1], pz = pos[n*3+2];
    float rx = pos[id0*3+0] - px;
    float ry = pos[id0*3+1] - py;
    float rz = pos[id0*3+2] - pz;
    bool anyact = false;
    int khalf = lane >> 5;
    #pragma unroll
    for (int i = 0; i < 8; ++i) {
      int k = 2*i + khalf;
      if (k < KP) {
        float dx = rx - kpts[k*3+0];
        float dy = ry - kpts[k*3+1];
        float dz = rz - kpts[k*3+2];
        float d = sqrtf(dx*dx + dy*dy + dz*dz);
        float h = 1.0f - d * SIGMA_INV;
        h = h > 0.0f ? h : 0.0f;
        h_lds[w][myj][k] = h;
        anyact |= (h > 0.0f);
      }
    }
    unsigned long long bal = __ballot(anyact);
    int active = (bal != 0ull) ? 1 : 0;
    if (active) {
      float acc[KP];
      #pragma unroll
      for (int k = 0; k < KP; ++k) acc[k] = 0.0f;
      unsigned int actj = (unsigned int)(bal | (bal >> 32));
      while (actj) {
        int j = __ffs(actj) - 1;
        actj &= actj - 1;
        int id = __shfl(id0, j);
        float f = feats[(size_t)id*DIN + lane];
        #pragma unroll
        for (int k = 0; k < KP; ++k) acc[k] += h_lds[w][j][k] * f;
      }
      size_t base = (size_t)n*KDIM;
      #pragma unroll
      for (int k = 0; k < KP; ++k)
        g[base + k*DIN + lane] = __float2bfloat16(acc[k]);
    }
    if (lane == 0) {
      flag[n] = active;
      if (active) atomicAdd(&cnts, 1);
    }
  }
  __syncthreads();
  if (tid == 0 && cnts) atomicAdd(&bcnt[blockIdx.x >> 6], cnts);
}

// ---------------- Kernel S: scan 196 segment counts (1 block) ---------------
__global__ __launch_bounds__(256) void scan_kernel(
    const int* __restrict__ blockcnt, int* __restrict__ blockoff,
    int* __restrict__ mact) {
  __shared__ int s[256];
  int tid = threadIdx.x;
  int own = (tid < NSEG) ? blockcnt[tid] : 0;
  s[tid] = own;
  __syncthreads();
  for (int d = 1; d < 256; d <<= 1) {
    int v = (tid >= d) ? s[tid-d] : 0;
    __syncthreads();
    s[tid] += v;
    __syncthreads();
  }
  if (tid < NSEG) blockoff[tid] = s[tid] - own;   // exclusive
  if (tid == NSEG-1) *mact = s[tid];
}

// ---------------- Kernel C0: fill rowlist + compact batch ids ---------------
// rowlist/bidc pre-memset (0 / -1) so tail slots are safely masked.
__global__ __launch_bounds__(256) void fill_kernel(
    const int* __restrict__ flag, const int* __restrict__ blockoff,
    const int* __restrict__ batch, int* __restrict__ rowlist,
    int* __restrict__ bidc) {
  __shared__ int s[256];
  int tid = threadIdx.x;
  int n = blockIdx.x*256 + tid;
  int f = (n < N_PTS) ? flag[n] : 0;
  s[tid] = f;
  __syncthreads();
  for (int d = 1; d < 256; d <<= 1) {
    int v = (tid >= d) ? s[tid-d] : 0;
    __syncthreads();
    s[tid] += v;
    __syncthreads();
  }
  if (f) {
    int sl = blockoff[blockIdx.x] + s[tid] - 1;
    rowlist[sl] = n;
    bidc[sl] = batch[n];
  }
}

// ---------------- Kernel 2: MFMA GEMM (gathered A rows) + fused pool --------
// 128x64 tile, BK=32, 4 waves 2x2 (each 64x32 out). A rows gathered via
// rowlist (per-lane global src of global_load_lds). Grid (392,16): linear id
// = rb + 392*cb, 392%8==0 -> all 16 cb blocks of one A-panel on ONE XCD.
__global__ __launch_bounds__(256) void gemm_mfma_pool(
    const __hip_bfloat16* __restrict__ g, const __hip_bfloat16* __restrict__ Wt,
    const int* __restrict__ rowlist, const int* __restrict__ bidc,
    const int* __restrict__ mact, float* __restrict__ partial) {
  __shared__ __align__(16) char lA[BM*64];   // 8KB
  __shared__ __align__(16) char lB[BN*64];   // 4KB
  __shared__ float psum[NB][BN];             // 4KB
  __shared__ int bid[BM];
  int rb = blockIdx.x, cb = blockIdx.y;
  int Ma = *mact;
  int r0 = rb*BM, c0 = cb*BN;
  int tid = threadIdx.x;
  if (r0 >= Ma) return;
  int lane = tid & 63, w = tid >> 6;
  int wr = w >> 1, wc = w & 1;

  // hoisted gather bases: thread stages LDS rows ra and 64+ra, chunk tid&3
  int ra = tid >> 2;
  int kg = (tid & 3) ^ ((ra >> 1) & 3);
  const char* pA0 = (const char*)(g + (size_t)rowlist[r0 + ra]*KDIM)      + kg*16;
  const char* pA1 = (const char*)(g + (size_t)rowlist[r0 + 64 + ra]*KDIM) + kg*16;
  const char* pB  = (const char*)(Wt + (size_t)(c0 + ra)*KDIM)            + kg*16;

  if (tid < BM) bid[tid] = bidc[r0 + tid];   // -1 padded past Ma
  for (int z = tid; z < NB*BN; z += 256) (&psum[0][0])[z] = 0.0f;

  f32x4 acc[4][2] = {};

  for (int k0 = 0; k0 < KDIM; k0 += BK) {
    GLD16(pA0 + k0*2, lA + tid*16);
    GLD16(pA1 + k0*2, lA + (256 + tid)*16);
    GLD16(pB  + k0*2, lB + tid*16);
    __syncthreads();
    bf16x8 af[4], bfr[2];
    #pragma unroll
    for (int m = 0; m < 4; ++m) {
      int row = wr*64 + m*16 + (lane & 15);
      int slot = (lane >> 4) ^ ((row >> 1) & 3);
      af[m] = *(const bf16x8*)(lA + row*64 + slot*16);
    }
    #pragma unroll
    for (int n = 0; n < 2; ++n) {
      int row = wc*32 + n*16 + (lane & 15);
      int slot = (lane >> 4) ^ ((row >> 1) & 3);
      bfr[n] = *(const bf16x8*)(lB + row*64 + slot*16);
    }
    #pragma unroll
    for (int m = 0; m < 4; ++m)
      #pragma unroll
      for (int n = 0; n < 2; ++n)
        acc[m][n] = __builtin_amdgcn_mfma_f32_16x16x32_bf16(af[m], bfr[n], acc[m][n], 0, 0, 0);
    __syncthreads();
  }

  // ---- epilogue: leaky + deterministic per-batch column sums ----
  int q = lane >> 4;
  #pragma unroll 1
  for (int phase = 0; phase < 8; ++phase) {
    if (wr*4 + q == phase) {
      #pragma unroll
      for (int n = 0; n < 2; ++n) {
        int c = wc*32 + n*16 + (lane & 15);
        float run = 0.0f; int curb = -2;
        #pragma unroll
        for (int m = 0; m < 4; ++m) {
          #pragma unroll
          for (int j = 0; j < 4; ++j) {
            int r = wr*64 + m*16 + q*4 + j;
            int b = bid[r];
            float v = acc[m][n][j];
            v = v > 0.0f ? v : 0.1f*v;
            if (b != curb) { if (curb >= 0) psum[curb][c] += run; run = 0.0f; curb = b; }
            run += v;
          }
        }
        if (curb >= 0) psum[curb][c] += run;
      }
    }
    __syncthreads();
  }
  for (int z = tid; z < NB*BN; z += 256) {
    int b = z >> 6, c = z & 63;
    partial[((size_t)rb*NB + b)*DOUT + c0 + c] = psum[b][c];
  }
}

// ---------------- Kernel 3: reduce ACTIVE partials -> pooled mean ------------
__global__ __launch_bounds__(256) void reduce_pool_kernel(
    const float* __restrict__ partial, const int* __restrict__ batch,
    const int* __restrict__ mact, float* __restrict__ pooled) {
  int b = blockIdx.y;
  int c = blockIdx.x*256 + threadIdx.x;
  int nact = (*mact + BM - 1) / BM;
  float s0=0.f, s1=0.f, s2=0.f, s3=0.f;
  int rb = 0;
  for (; rb + 4 <= nact; rb += 4) {
    s0 += partial[((size_t)(rb+0)*NB + b)*DOUT + c];
    s1 += partial[((size_t)(rb+1)*NB + b)*DOUT + c];
    s2 += partial[((size_t)(rb+2)*NB + b)*DOUT + c];
    s3 += partial[((size_t)(rb+3)*NB + b)*DOUT + c];
  }
  for (; rb < nact; ++rb) s0 += partial[((size_t)rb*NB + b)*DOUT + c];
  float s = (s0+s1)+(s2+s3);
  int lb, ub;
  { int l = 0, r = N_PTS; while (l < r) { int m = (l+r)>>1; if (batch[m] <  b) l = m+1; else r = m; } lb = l; }
  { int l = 0, r = N_PTS; while (l < r) { int m = (l+r)>>1; if (batch[m] <= b) l = m+1; else r = m; } ub = l; }
  float cnt = (float)(ub - lb);
  pooled[b*DOUT + c] = s / fmaxf(cnt, 1.0f);
}

// ---------------- MLP: split-K for parallelism ------------------------------
__global__ __launch_bounds__(512) void mlpA_kernel(
    const float* __restrict__ pooled, const float* __restrict__ w1,
    float* __restrict__ part1) {
  __shared__ float pl[128];
  int s = blockIdx.x, b = blockIdx.y;
  int o = threadIdx.x;
  if (o < 128) pl[o] = pooled[b*DOUT + s*128 + o];
  __syncthreads();
  float acc = 0.0f;
  #pragma unroll 8
  for (int i = 0; i < 128; ++i) acc += pl[i] * w1[(size_t)(s*128 + i)*512 + o];
  part1[((size_t)b*8 + s)*512 + o] = acc;
}

__global__ __launch_bounds__(256) void mlpB_kernel(
    const float* __restrict__ part1, const float* __restrict__ b1,
    const float* __restrict__ w2, float* __restrict__ part2) {
  __shared__ float hs[128];
  int s2 = blockIdx.x, b = blockIdx.y;
  int t = threadIdx.x;
  if (t < 128) {
    int i2 = s2*128 + t;
    float v = b1[i2];
    #pragma unroll
    for (int s = 0; s < 8; ++s) v += part1[((size_t)b*8 + s)*512 + i2];
    hs[t] = fmaxf(v, 0.0f);
  }
  __syncthreads();
  float acc = 0.0f;
  #pragma unroll 8
  for (int j = 0; j < 128; ++j) acc += hs[j] * w2[(size_t)(s2*128 + j)*256 + t];
  part2[((size_t)b*4 + s2)*256 + t] = acc;
}

__global__ __launch_bounds__(256) void mlpC_kernel(
    const float* __restrict__ part2, const float* __restrict__ b2,
    const float* __restrict__ w3, const float* __restrict__ b3,
    float* __restrict__ out) {
  __shared__ float h2l[256];
  int b = blockIdx.x;
  int t = threadIdx.x;
  float v = b2[t];
  #pragma unroll
  for (int s2 = 0; s2 < 4; ++s2) v += part2[((size_t)b*4 + s2)*256 + t];
  h2l[t] = fmaxf(v, 0.0f);
  __syncthreads();
  if (t < 152) {
    float acc = b3[t];
    #pragma unroll 8
    for (int i = 0; i < 256; ++i) acc += h2l[i] * w3[i*152 + t];
    out[b*152 + t] = acc;
  }
}

// ---------------- launch -----------------------------------------------------
extern "C" void kernel_launch(void* const* d_in, const int* in_sizes, int n_in,
                              void* d_out, int out_size, void* d_ws, size_t ws_size,
                              hipStream_t stream) {
  (void)in_sizes; (void)n_in; (void)out_size; (void)ws_size;
  const float* pos   = (const float*)d_in[0];
  const float* feats = (const float*)d_in[1];
  const float* kpts  = (const float*)d_in[2];
  const float* kpw   = (const float*)d_in[3];
  const float* w1    = (const float*)d_in[4];
  const float* b1    = (const float*)d_in[5];
  const float* w2    = (const float*)d_in[6];
  const float* b2    = (const float*)d_in[7];
  const float* w3    = (const float*)d_in[8];
  const float* b3    = (const float*)d_in[9];
  const int* nidx    = (const int*)d_in[10];
  const int* batch   = (const int*)d_in[11];
  float* out = (float*)d_out;

  char* ws = (char*)d_ws;
  const size_t off_g        = 0;                         // 50176*960*2   = 96,337,920
  const size_t off_bidc     = 96337920;                  // 50176*4       = 200,704
  const size_t off_rowlist  = off_bidc + 200704;         // 200,704
  const size_t off_flag     = off_rowlist + 200704;      // 200,704
  const size_t off_bcnt     = off_flag + 200704;         // 1024 (196 used)
  const size_t off_boff     = off_bcnt + 1024;           // 1024
  const size_t off_mact     = off_boff + 1024;           // 64
  const size_t off_wt       = off_mact + 64;             // 1024*960*2    = 1,966,080
  const size_t off_partial  = off_wt + 1966080;          // 392*16*1024*4 = 25,690,112
  const size_t off_pooled   = off_partial + 25690112;    // 65,536
  const size_t off_p1       = off_pooled + 65536;        // 262,144
  const size_t off_p2       = off_p1 + 262144;           // 65,536
  __hip_bfloat16* g  = (__hip_bfloat16*)(ws + off_g);
  int* bidc    = (int*)(ws + off_bidc);
  int* rowlist = (int*)(ws + off_rowlist);
  int* flag    = (int*)(ws + off_flag);
  int* bcnt    = (int*)(ws + off_bcnt);
  int* boff    = (int*)(ws + off_boff);
  int* mact    = (int*)(ws + off_mact);
  __hip_bfloat16* wt = (__hip_bfloat16*)(ws + off_wt);
  float* partial = (float*)(ws + off_partial);
  float* pooled  = (float*)(ws + off_pooled);
  float* part1   = (float*)(ws + off_p1);
  float* part2   = (float*)(ws + off_p2);

  hipMemsetAsync(bcnt, 0, 1024, stream);
  hipMemsetAsync(rowlist, 0, 200704, stream);
  hipMemsetAsync(bidc, 0xFF, 200704, stream);          // -1 everywhere
  wt_kernel<<<dim3(KDIM/64, DOUT/64), 256, 0, stream>>>(kpw, wt);
  kpconv_full_kernel<<<N_PTS/4, 256, 0, stream>>>(pos, feats, kpts, nidx, g, flag, bcnt);
  scan_kernel<<<1, 256, 0, stream>>>(bcnt, boff, mact);
  fill_kernel<<<NSEG, 256, 0, stream>>>(flag, boff, batch, rowlist, bidc);
  gemm_mfma_pool<<<dim3(RB_FULL, 16), 256, 0, stream>>>(g, wt, rowlist, bidc, mact, partial);
  reduce_pool_kernel<<<dim3(DOUT/256, NB), 256, 0, stream>>>(partial, batch, mact, pooled);
  mlpA_kernel<<<dim3(8, NB), 512, 0, stream>>>(pooled, w1, part1);
  mlpB_kernel<<<dim3(4, NB), 256, 0, stream>>>(part1, b1, w2, part2);
  mlpC_kernel<<<NB, 256, 0, stream>>>(part2, b2, w3, b3, out);
}